// Round 2
// baseline (484.682 us; speedup 1.0000x reference)
//
#include <hip/hip_runtime.h>

#define D 1024
#define K 64
#define NROWS 8192

// clang-native float4 so __builtin_nontemporal_load accepts it
typedef float nf4 __attribute__((ext_vector_type(4)));

// ---------------------------------------------------------------------------
// Workspace layout (total ~2.3 MB):
//   M: K*D floats (256 KB)   M[k,d] = V[k,d] + sum_e W[k,d,e]*x2[e]
//   c: 64 floats             c[k]   = b[k]   + sum_e V[k,D+e]*x2[e]
//   s: NROWS*K floats (2 MB) s[n,k] = sum_d x1[n,d]*M[k,d]  (atomic split-K)
//
// Measurement note: the timed window contains two 1-GiB harness ws-poison
// fills (~321 us, fixed). Our kernel slice is ~78 us with a ~48 us floor
// (256 MB W + 32 MB x1 mandatory reads). This version removes the only
// non-mandatory HBM traffic (the 32 MB split-K partial round-trip).
// ---------------------------------------------------------------------------

// ---------------------------------------------------------------------------
// k1: one wave per row of M (65536 rows, 4KB each) + 64 rows for c.
// x2 staged in LDS; lane reads 4x float4 (16 floats), nontemporal (W is
// streamed exactly once -- don't evict M/x1 from L2/L3).
// Also zeroes s[] (first 2048 blocks, 1 float/thread) for k2's atomics.
// ---------------------------------------------------------------------------
__global__ __launch_bounds__(256) void k1_wx2(
    const float* __restrict__ W, const float* __restrict__ V,
    const float* __restrict__ x2, const float* __restrict__ b,
    float* __restrict__ M, float* __restrict__ c, float* __restrict__ s) {
  __shared__ float xsh[D];
  int t = threadIdx.x;

  // zero the atomic accumulator: 2048 blocks * 256 threads = 524288 = NROWS*K
  if (blockIdx.x < (NROWS * K / 256)) s[(long)blockIdx.x * 256 + t] = 0.f;

  ((float4*)xsh)[t] = ((const float4*)x2)[t];  // 256 threads * 16B = 4KB
  __syncthreads();

  int lane = t & 63;
  int wv = t >> 6;
  long row = (long)blockIdx.x * 4 + wv;  // 0..65599
  const long WROWS = (long)K * D;        // 65536

  const float* src;
  bool is_w = (row < WROWS);
  if (is_w) {
    src = W + row * D;
  } else {
    long k = row - WROWS;
    if (k >= K) return;
    src = V + k * (2 * D) + D;  // V[k, D:2D]
  }

  const nf4* s4 = (const nf4*)src;
  const float4* x4 = (const float4*)xsh;
  float sum = 0.f;
#pragma unroll
  for (int it = 0; it < 4; ++it) {
    nf4 w = __builtin_nontemporal_load(&s4[lane + it * 64]);
    float4 xv = x4[lane + it * 64];
    sum += w.x * xv.x + w.y * xv.y + w.z * xv.z + w.w * xv.w;
  }
#pragma unroll
  for (int off = 32; off; off >>= 1) sum += __shfl_down(sum, off, 64);

  if (lane == 0) {
    if (is_w) {
      long k = row >> 10;
      long d = row & (D - 1);
      M[row] = sum + V[k * (2 * D) + d];  // fold V1 into M
    } else {
      long k = row - WROWS;
      c[k] = sum + b[k];
    }
  }
}

// ---------------------------------------------------------------------------
// k2: s[n,k] += sum_{d in split} x1[n,d]*M[k,d].
// Block tile 256n x 64k, 256 threads, 8n x 8k register tile. NSPLIT-way
// d-split -> 256 blocks (one per CU). Register-prefetch double buffering:
// chunk i+1's global loads issue right after the staging barrier so they
// overlap the 1024-FMA compute phase. Epilogue: unsafeAtomicAdd into the
// shared 2 MB s buffer (hw global_atomic_add_f32, L2-resident, fire-and-
// forget) instead of a 16 MB per-split partial buffer.
// ---------------------------------------------------------------------------
template <int NSPLIT>
__global__ __launch_bounds__(256, 3) void k2_gemm(
    const float* __restrict__ x1, const float* __restrict__ M,
    float* __restrict__ s) {
  __shared__ float xs[16][256];
  __shared__ float ms[16][64];
  int t = threadIdx.x;
  int nt = blockIdx.x / NSPLIT;
  int sp = blockIdx.x % NSPLIT;
  const int DSP = D / NSPLIT;
  const int NIT = DSP / 16;
  int n0 = nt * 256;
  int d0 = sp * DSP;

  int tx = t & 7;   // k-group: k = tx*8 .. +7
  int ty = t >> 3;  // n-group: n = n0 + ty*8 .. +7
  int mk = t & 63;  // M staging: row
  int mg = t >> 6;  // M staging: d-quad 0..3

  const nf4* xrow = (const nf4*)(x1 + (long)(n0 + t) * D + d0);
  const float4* mrow = (const float4*)(M + (long)mk * D + d0) + mg;

  float acc[8][8];
#pragma unroll
  for (int i = 0; i < 8; ++i)
#pragma unroll
    for (int j = 0; j < 8; ++j) acc[i][j] = 0.f;

  // prologue: prefetch chunk 0 into registers (x1 is read-once: nontemporal)
  nf4 xreg[4];
  float4 mreg;
#pragma unroll
  for (int h = 0; h < 4; ++h) xreg[h] = __builtin_nontemporal_load(&xrow[h]);
  mreg = mrow[0];

#pragma unroll 1
  for (int it = 0; it < NIT; ++it) {
    // stage regs -> LDS (x1: thread t owns row n0+t, 16 consecutive d's)
#pragma unroll
    for (int h = 0; h < 4; ++h) {
      xs[h * 4 + 0][t] = xreg[h].x;
      xs[h * 4 + 1][t] = xreg[h].y;
      xs[h * 4 + 2][t] = xreg[h].z;
      xs[h * 4 + 3][t] = xreg[h].w;
    }
    ms[mg * 4 + 0][mk] = mreg.x;
    ms[mg * 4 + 1][mk] = mreg.y;
    ms[mg * 4 + 2][mk] = mreg.z;
    ms[mg * 4 + 3][mk] = mreg.w;
    __syncthreads();

    // prefetch chunk it+1 (overlaps with compute below)
    if (it + 1 < NIT) {
#pragma unroll
      for (int h = 0; h < 4; ++h)
        xreg[h] = __builtin_nontemporal_load(&xrow[(it + 1) * 4 + h]);
      mreg = mrow[(it + 1) * 4];
    }

#pragma unroll
    for (int d = 0; d < 16; ++d) {
      float4 a0 = *(const float4*)&xs[d][ty * 8];
      float4 a1 = *(const float4*)&xs[d][ty * 8 + 4];
      float4 b0 = *(const float4*)&ms[d][tx * 8];
      float4 b1 = *(const float4*)&ms[d][tx * 8 + 4];
      float xa[8] = {a0.x, a0.y, a0.z, a0.w, a1.x, a1.y, a1.z, a1.w};
      float mb[8] = {b0.x, b0.y, b0.z, b0.w, b1.x, b1.y, b1.z, b1.w};
#pragma unroll
      for (int i = 0; i < 8; ++i)
#pragma unroll
        for (int j = 0; j < 8; ++j)
          acc[i][j] = fmaf(xa[i], mb[j], acc[i][j]);
    }
    __syncthreads();
  }

  // epilogue: accumulate into s[n][k] (device-scope hw f32 atomic add).
  // 8-way collision per element max (one per d-split), spread over 64 KB.
  float* dst = s + (long)(n0 + ty * 8) * K + tx * 8;
#pragma unroll
  for (int i = 0; i < 8; ++i)
#pragma unroll
    for (int j = 0; j < 8; ++j)
      unsafeAtomicAdd(&dst[(long)i * K + j], acc[i][j]);
}

// ---------------------------------------------------------------------------
// k3: out[n] = sum_k relu(s[n,k] + c[k]) * U[k]
// One wave per row, lane = k (K==64 exactly). Only 2 MB read now (L3-hot).
// ---------------------------------------------------------------------------
__global__ __launch_bounds__(256) void k3_final(
    const float* __restrict__ s, const float* __restrict__ c,
    const float* __restrict__ U, float* __restrict__ out) {
  int t = threadIdx.x;
  int lane = t & 63;
  int n = blockIdx.x * 4 + (t >> 6);
  float v = fmaxf(s[(long)n * K + lane] + c[lane], 0.f) * U[lane];
#pragma unroll
  for (int off = 32; off; off >>= 1) v += __shfl_down(v, off, 64);
  if (lane == 0) out[n] = v;
}

extern "C" void kernel_launch(void* const* d_in, const int* in_sizes, int n_in,
                              void* d_out, int out_size, void* d_ws, size_t ws_size,
                              hipStream_t stream) {
  const float* x1 = (const float*)d_in[0];  // (8192, 1024)
  const float* x2 = (const float*)d_in[1];  // (1, 1024)
  const float* V = (const float*)d_in[2];   // (64, 2048)
  const float* W = (const float*)d_in[3];   // (64, 1024, 1024)
  const float* b = (const float*)d_in[4];   // (64,)
  const float* U = (const float*)d_in[5];   // (64, 1)
  float* out = (float*)d_out;               // (8192, 1)

  float* M = (float*)d_ws;            // 65536 floats (256 KB)
  float* c = M + (long)K * D;         // 64 floats
  float* s = c + 64;                  // 524288 floats (2 MB), 16B-aligned

  // k1: 65600 rows, 4 waves/block, 1 row/wave; also zeroes s
  k1_wx2<<<dim3(16400), dim3(256), 0, stream>>>(W, V, x2, b, M, c, s);

  // k2: 32 n-tiles * 8 d-splits = 256 blocks -> all CUs busy
  k2_gemm<8><<<dim3(256), dim3(256), 0, stream>>>(x1, M, s);

  // k3: 2048 blocks, 4 rows each
  k3_final<<<dim3(NROWS / 4), dim3(256), 0, stream>>>(s, c, U, out);
}